// Round 13
// baseline (432.640 us; speedup 1.0000x reference)
//
#include <hip/hip_runtime.h>
#include <hip/hip_fp16.h>

#define N_NODES 100000
#define N_EDGES 3200000
#define NUM_FEATURES 128
#define DIM 10
#define NUM_GRAPHS 64

#define BSHIFT 8                             // 256 nodes per bucket
#define BSIZE (1 << BSHIFT)
#define NB ((N_NODES + BSIZE - 1) / BSIZE)   // 391 buckets
#define CHUNKS 2                             // spmm1 chunks per bucket (R5-proven)
#define EPB 6250                             // edges per placement block
#define PLACE_BLOCKS 512                     // 512 * 6250 = 3.2M exact
#define NQUAD 25000                          // 100k nodes / 4 per 32-lane group
#define GEMM_BLOCKS 1563                     // ceil(25000*32 / 512)
#define BOUND_BLOCKS 196                     // ceil(100000 / 512)
#define TILE (BSIZE * DIM)                   // 2560 floats per bucket part tile
#define CAP 4608                             // max edges per spmm1 chunk (+11 sigma)
#define CAPB 16384                           // per-bucket pk region capacity (+90 sigma)
#define CAPB2 10240                          // per-src-bucket pk2 capacity (fill 8192+-90, +22 sigma)
#define NCHUNK (NB * CHUNKS)                 // 782
#define ACC_STRIDE 11

// f32 add of DPP row-rotated value (VALU pipe)
#define DPP_ROR_ADD(v, n)                                                        \
    (v) += __int_as_float(__builtin_amdgcn_update_dpp(                           \
        0, __float_as_int(v), 0x120 | (n), 0xF, 0xF, false))

// ---------------------------------------------------------------------------
// Fused front-end. R13: placement builds TWO edge arrays:
//   pk  (dst-bucketed):  (dst&255)<<17 | src          -> spmm1 gather
//   pk2 (src-bucketed):  (src&255)<<17 | gids[dst]    -> pass2 src-major
// Baking graph(dst) into pk2 costs 1 random 4B gather/edge here (~1 TA
// line-touch) and removes pass2's 5-lane 20B gather/edge (~5 touches).
// Lessons ledger: R3 no cross-block fences (per-XCD L2 wb+inv = 3x). R6 no
// pk line-padding. R7 no k-indexed LDS W1. R8/R9 W1 already loaded once.
// R10 no 32B padded rows. R11 no f32 gather table (breaks L2 residency).
// R12 place-block count is a wash (write-amp offsets tail) -> keep 512 for
// the now-heavier latency-bound placement.
// ---------------------------------------------------------------------------
__global__ __launch_bounds__(512) void k_front(const float* __restrict__ feat,
                                               const float* __restrict__ W1,
                                               __half* __restrict__ h1,
                                               const int* __restrict__ gids,
                                               int* __restrict__ bound,
                                               const int* __restrict__ src,
                                               const int* __restrict__ dst,
                                               int* __restrict__ cnt,
                                               int* __restrict__ cnt2,
                                               int* __restrict__ pk,
                                               int* __restrict__ pk2) {
    __shared__ int hd[NB];      // dst histogram
    __shared__ int cb[NB];      // dst write cursors
    __shared__ int hs[NB];      // src histogram
    __shared__ int cb2[NB];     // src write cursors

    if (blockIdx.x < PLACE_BLOCKS) {
        int base0 = blockIdx.x * EPB;
        for (int t = threadIdx.x; t < NB; t += 512) { hd[t] = 0; hs[t] = 0; }
        __syncthreads();

        // phase 1: dual histogram (coalesced 4-batched dst+src loads)
        {
            int i = threadIdx.x;
            for (; i + 1536 < EPB; i += 2048) {
                int d0 = dst[base0 + i],        d1 = dst[base0 + i + 512];
                int d2 = dst[base0 + i + 1024], d3 = dst[base0 + i + 1536];
                int s0 = src[base0 + i],        s1 = src[base0 + i + 512];
                int s2 = src[base0 + i + 1024], s3 = src[base0 + i + 1536];
                atomicAdd(&hd[d0 >> BSHIFT], 1);
                atomicAdd(&hd[d1 >> BSHIFT], 1);
                atomicAdd(&hd[d2 >> BSHIFT], 1);
                atomicAdd(&hd[d3 >> BSHIFT], 1);
                atomicAdd(&hs[s0 >> BSHIFT], 1);
                atomicAdd(&hs[s1 >> BSHIFT], 1);
                atomicAdd(&hs[s2 >> BSHIFT], 1);
                atomicAdd(&hs[s3 >> BSHIFT], 1);
            }
            for (; i < EPB; i += 512) {
                atomicAdd(&hd[dst[base0 + i] >> BSHIFT], 1);
                atomicAdd(&hs[src[base0 + i] >> BSHIFT], 1);
            }
        }
        __syncthreads();

        // phase 2: reserve contiguous ranges in both bucket regions
        for (int t = threadIdx.x; t < NB; t += 512) {
            int c = hd[t];
            int o = c ? atomicAdd(&cnt[t], c) : 0;
            cb[t] = t * CAPB + o;
            int c2 = hs[t];
            int o2 = c2 ? atomicAdd(&cnt2[t], c2) : 0;
            cb2[t] = t * CAPB2 + o2;
        }
        __syncthreads();

        // phase 3: place both (dst/src re-reads L2-hot; gids[d] random gather;
        //          1 LDS atomic per edge per array; clamps = memory safety)
        {
            int i = threadIdx.x;
            for (; i + 1536 < EPB; i += 2048) {
                int d0 = dst[base0 + i],        d1 = dst[base0 + i + 512];
                int d2 = dst[base0 + i + 1024], d3 = dst[base0 + i + 1536];
                int s0 = src[base0 + i],        s1 = src[base0 + i + 512];
                int s2 = src[base0 + i + 1024], s3 = src[base0 + i + 1536];
                int g0 = gids[d0], g1 = gids[d1], g2 = gids[d2], g3 = gids[d3];
                int q0 = atomicAdd(&cb[d0 >> BSHIFT], 1);
                int q1 = atomicAdd(&cb[d1 >> BSHIFT], 1);
                int q2 = atomicAdd(&cb[d2 >> BSHIFT], 1);
                int q3 = atomicAdd(&cb[d3 >> BSHIFT], 1);
                if (q0 < ((d0 >> BSHIFT) + 1) * CAPB) pk[q0] = ((d0 & (BSIZE - 1)) << 17) | s0;
                if (q1 < ((d1 >> BSHIFT) + 1) * CAPB) pk[q1] = ((d1 & (BSIZE - 1)) << 17) | s1;
                if (q2 < ((d2 >> BSHIFT) + 1) * CAPB) pk[q2] = ((d2 & (BSIZE - 1)) << 17) | s2;
                if (q3 < ((d3 >> BSHIFT) + 1) * CAPB) pk[q3] = ((d3 & (BSIZE - 1)) << 17) | s3;
                int w0 = atomicAdd(&cb2[s0 >> BSHIFT], 1);
                int w1 = atomicAdd(&cb2[s1 >> BSHIFT], 1);
                int w2 = atomicAdd(&cb2[s2 >> BSHIFT], 1);
                int w3 = atomicAdd(&cb2[s3 >> BSHIFT], 1);
                if (w0 < ((s0 >> BSHIFT) + 1) * CAPB2) pk2[w0] = ((s0 & (BSIZE - 1)) << 17) | g0;
                if (w1 < ((s1 >> BSHIFT) + 1) * CAPB2) pk2[w1] = ((s1 & (BSIZE - 1)) << 17) | g1;
                if (w2 < ((s2 >> BSHIFT) + 1) * CAPB2) pk2[w2] = ((s2 & (BSIZE - 1)) << 17) | g2;
                if (w3 < ((s3 >> BSHIFT) + 1) * CAPB2) pk2[w3] = ((s3 & (BSIZE - 1)) << 17) | g3;
            }
            for (; i < EPB; i += 512) {
                int d = dst[base0 + i];
                int s = src[base0 + i];
                int g = gids[d];
                int q = atomicAdd(&cb[d >> BSHIFT], 1);
                if (q < ((d >> BSHIFT) + 1) * CAPB) pk[q] = ((d & (BSIZE - 1)) << 17) | s;
                int w = atomicAdd(&cb2[s >> BSHIFT], 1);
                if (w < ((s >> BSHIFT) + 1) * CAPB2) pk2[w] = ((s & (BSIZE - 1)) << 17) | g;
            }
        }
        return;
    }

    // ---- GEMM half: 4 nodes per 32-lane group ----
    int bb = blockIdx.x - PLACE_BLOCKS;

    // fused graph-boundary computation (gids sorted)
    int nb2 = bb * 512 + threadIdx.x;
    if (bb < BOUND_BLOCKS && nb2 < N_NODES) {
        int g  = gids[nb2];
        int gp = nb2 ? gids[nb2 - 1] : -1;
        for (int v = gp + 1; v <= g; ++v) bound[v] = nb2;
        if (nb2 == N_NODES - 1)
            for (int v = g + 1; v <= NUM_GRAPHS; ++v) bound[v] = N_NODES;
    }

    int gid  = bb * 512 + threadIdx.x;
    int quad = gid >> 5;                 // node quad id
    int lane = gid & 31;
    if (quad >= NQUAD) return;

    // lane's W1 slice (rows lane*4..lane*4+3, 160B contiguous) as 10 dwordx4
    float wf[40];
    {
        const float4* W14 = reinterpret_cast<const float4*>(W1 + lane * 40);
#pragma unroll
        for (int m = 0; m < 10; ++m) {
            float4 q = W14[m];
            wf[4 * m]     = q.x;
            wf[4 * m + 1] = q.y;
            wf[4 * m + 2] = q.z;
            wf[4 * m + 3] = q.w;
        }
    }

    int nbase = quad * 4;
    float4 f[4];
#pragma unroll
    for (int n = 0; n < 4; ++n)
        f[n] = *reinterpret_cast<const float4*>(feat + (size_t)(nbase + n) * NUM_FEATURES + lane * 4);

    float acc[4][DIM];
#pragma unroll
    for (int n = 0; n < 4; ++n)
#pragma unroll
        for (int k = 0; k < DIM; ++k) acc[n][k] = 0.f;

#pragma unroll
    for (int n = 0; n < 4; ++n) {
        float fv[4] = {f[n].x, f[n].y, f[n].z, f[n].w};
#pragma unroll
        for (int j = 0; j < 4; ++j)
#pragma unroll
            for (int k = 0; k < DIM; ++k)
                acc[n][k] += fv[j] * wf[j * DIM + k];
    }

    // reduce over 32 lanes: 4 in-row DPP rotate-adds (VALU) + 1 shfl_xor(16)
#pragma unroll
    for (int n = 0; n < 4; ++n)
#pragma unroll
        for (int k = 0; k < DIM; ++k) {
            float v = acc[n][k];
            DPP_ROR_ADD(v, 1);
            DPP_ROR_ADD(v, 2);
            DPP_ROR_ADD(v, 4);
            DPP_ROR_ADD(v, 8);
            acc[n][k] = v + __shfl_xor(v, 16);
        }

    if (lane == 0) {
        __half2* o = (__half2*)h1;
#pragma unroll
        for (int n = 0; n < 4; ++n)
#pragma unroll
            for (int j = 0; j < 5; ++j)
                o[(size_t)(nbase + n) * 5 + j] = __floats2half2_rn(acc[n][2 * j], acc[n][2 * j + 1]);
    }
}

// ---------------------------------------------------------------------------
// Pass 1 SpMM (R5-proven, CHUNKS=2): in-block counting sort to exact dst-loc
// (eh stash, 2 LDS atomics/edge, 4-batched pk loads), exclusive-owner
// segmented gather (12 slots x 5 lanes, 8-deep), register acc, non-atomic
// writes.
// ---------------------------------------------------------------------------
__global__ __launch_bounds__(512) void k_spmm1(const __half* __restrict__ h,
                                               const int* __restrict__ cnt,
                                               const int* __restrict__ pk,
                                               float* __restrict__ part) {
    __shared__ int eh[CAP];
    __shared__ int srt[CAP];
    __shared__ int hist[BSIZE];
    __shared__ int cur[BSIZE];

    int b     = blockIdx.x / CHUNKS;
    int chunk = blockIdx.x % CHUNKS;
    int s0  = b * CAPB;
    int len = cnt[b];
    int c0  = s0 + (len * chunk) / CHUNKS;
    int c1  = s0 + (len * (chunk + 1)) / CHUNKS;
    int n   = c1 - c0;
    int nc  = min(n, CAP);

    for (int t = threadIdx.x; t < BSIZE; t += 512) hist[t] = 0;
    __syncthreads();

    {
        int i = threadIdx.x;
        for (; i + 1536 < nc; i += 2048) {
            int p0 = pk[c0 + i],        p1 = pk[c0 + i + 512];
            int p2 = pk[c0 + i + 1024], p3 = pk[c0 + i + 1536];
            eh[i] = p0; eh[i + 512] = p1; eh[i + 1024] = p2; eh[i + 1536] = p3;
            atomicAdd(&hist[p0 >> 17], 1);
            atomicAdd(&hist[p1 >> 17], 1);
            atomicAdd(&hist[p2 >> 17], 1);
            atomicAdd(&hist[p3 >> 17], 1);
        }
        for (; i < nc; i += 512) {
            int p = pk[c0 + i];
            eh[i] = p;
            atomicAdd(&hist[p >> 17], 1);
        }
    }
    __syncthreads();

    if (threadIdx.x < 64) {
        int l = threadIdx.x;
        int carry = 0;
#pragma unroll
        for (int j = 0; j < 4; ++j) {
            int x = hist[j * 64 + l];
            int v = x;
#pragma unroll
            for (int off = 1; off < 64; off <<= 1) {
                int t2 = __shfl_up(v, off);
                if (l >= off) v += t2;
            }
            cur[j * 64 + l] = carry + v - x;
            carry += __shfl(v, 63);
        }
    }
    __syncthreads();

    for (int i = threadIdx.x; i < nc; i += 512) {
        int p = eh[i];
        int pos = atomicAdd(&cur[p >> 17], 1);
        srt[pos] = p;
    }
    __syncthreads();

    int wave = threadIdx.x >> 6;
    int lane = threadIdx.x & 63;
    int slot = lane / 5;            // 0..12 (12 = idle lanes 60..63)
    int l    = lane - slot * 5;     // half2 index within the row
    float* pb = part + (size_t)blockIdx.x * TILE;
    const __half2* h2 = (const __half2*)h;

    if (slot < 12) {
        int g = wave * 12 + slot;   // 0..95
        for (int loc = g; loc < BSIZE; loc += 96) {
            int e0 = loc ? cur[loc - 1] : 0;
            int e1 = cur[loc];
            float ax0 = 0.f, ay0 = 0.f, ax1 = 0.f, ay1 = 0.f;
            float ax2 = 0.f, ay2 = 0.f, ax3 = 0.f, ay3 = 0.f;
            int e = e0;
            for (; e + 7 < e1; e += 8) {
                float2 v0 = __half22float2(h2[(size_t)(srt[e]     & 0x1FFFF) * 5 + l]);
                float2 v1 = __half22float2(h2[(size_t)(srt[e + 1] & 0x1FFFF) * 5 + l]);
                float2 v2 = __half22float2(h2[(size_t)(srt[e + 2] & 0x1FFFF) * 5 + l]);
                float2 v3 = __half22float2(h2[(size_t)(srt[e + 3] & 0x1FFFF) * 5 + l]);
                float2 v4 = __half22float2(h2[(size_t)(srt[e + 4] & 0x1FFFF) * 5 + l]);
                float2 v5 = __half22float2(h2[(size_t)(srt[e + 5] & 0x1FFFF) * 5 + l]);
                float2 v6 = __half22float2(h2[(size_t)(srt[e + 6] & 0x1FFFF) * 5 + l]);
                float2 v7 = __half22float2(h2[(size_t)(srt[e + 7] & 0x1FFFF) * 5 + l]);
                ax0 += v0.x + v4.x; ay0 += v0.y + v4.y;
                ax1 += v1.x + v5.x; ay1 += v1.y + v5.y;
                ax2 += v2.x + v6.x; ay2 += v2.y + v6.y;
                ax3 += v3.x + v7.x; ay3 += v3.y + v7.y;
            }
            for (; e < e1; ++e) {
                float2 v = __half22float2(h2[(size_t)(srt[e] & 0x1FFFF) * 5 + l]);
                ax0 += v.x; ay0 += v.y;
            }
            pb[loc * DIM + 2 * l]     = (ax0 + ax1) + (ax2 + ax3);
            pb[loc * DIM + 2 * l + 1] = (ay0 + ay1) + (ay2 + ay3);
        }
    }
    __syncthreads();

    // overflow fallback (statistically never; correctness guard)
    for (int i = CAP + threadIdx.x; i < n; i += 512) {
        int p = pk[c0 + i];
        int loc = p >> 17, s = p & 0x1FFFF;
#pragma unroll
        for (int j = 0; j < 5; ++j) {
            float2 v = __half22float2(h2[(size_t)s * 5 + j]);
            atomicAdd(&pb[loc * DIM + 2 * j], v.x);
            atomicAdd(&pb[loc * DIM + 2 * j + 1], v.y);
        }
    }
}

// merge CHUNKS partials + fused relu -> r (fp16, compact stride 10)
__global__ __launch_bounds__(256) void k_merge_relu(const float* __restrict__ part,
                                                    __half* __restrict__ r) {
    int b     = blockIdx.x;
    int nbase = b << BSHIFT;
    const float* p0 = part + (size_t)(b * CHUNKS) * TILE;
    __half2* r2 = (__half2*)r;
    for (int t = threadIdx.x; t < TILE / 2; t += 256) {
        float sx = 0.f, sy = 0.f;
#pragma unroll
        for (int c = 0; c < CHUNKS; ++c) {
            float2 v = ((const float2*)(p0 + (size_t)c * TILE))[t];
            sx += v.x; sy += v.y;
        }
        int ebase = nbase * DIM + 2 * t;
        if (ebase < N_NODES * DIM)
            r2[(size_t)nbase * 5 + t] = __floats2half2_rn(fmaxf(sx, 0.f), fmaxf(sy, 0.f));
    }
}

// ---------------------------------------------------------------------------
// Pass 2 — SRC-MAJOR (R13 rewrite). One block per src-bucket: stage the
// bucket's 256 r-rows into LDS coalesced (2.5 KB), stream pk2 sequentially
// (graph id baked in at placement), accumulate into LDS acc[64][11], flush
// once to sums. Zero random global accesses — replaces 3.2M r[src] gathers.
// ---------------------------------------------------------------------------
__global__ __launch_bounds__(512) void k_pass2(const __half* __restrict__ r,
                                               const int* __restrict__ cnt2,
                                               const int* __restrict__ pk2,
                                               float* __restrict__ sums) {
    __shared__ __half2 lr[BSIZE * 5];                 // staged r rows (2.5 KB)
    __shared__ float acc[NUM_GRAPHS * ACC_STRIDE];    // 64 x 11 f32

    int b     = blockIdx.x;
    int nbase = b << BSHIFT;

    for (int t = threadIdx.x; t < NUM_GRAPHS * ACC_STRIDE; t += 512) acc[t] = 0.f;

    const __half2* r2 = (const __half2*)r;
    for (int t = threadIdx.x; t < BSIZE * 5; t += 512) {
        int node = nbase + t / 5;
        lr[t] = (node < N_NODES) ? r2[(size_t)node * 5 + (t - (t / 5) * 5)]
                                 : __floats2half2_rn(0.f, 0.f);
    }
    __syncthreads();

    int s0  = b * CAPB2;
    int len = min(cnt2[b], CAPB2);
    int c1  = s0 + len;

    for (int e = s0 + threadIdx.x; e < c1; e += 512) {
        int p   = pk2[e];
        int loc = p >> 17;
        int g   = p & 63;
        float* ag = &acc[g * ACC_STRIDE];
#pragma unroll
        for (int j = 0; j < 5; ++j) {
            float2 v = __half22float2(lr[loc * 5 + j]);
            atomicAdd(&ag[2 * j],     v.x);
            atomicAdd(&ag[2 * j + 1], v.y);
        }
    }
    __syncthreads();

    for (int t = threadIdx.x; t < NUM_GRAPHS * DIM; t += 512) {
        float v = acc[(t / DIM) * ACC_STRIDE + (t - (t / DIM) * DIM)];
        if (v != 0.f) atomicAdd(&sums[t], v);
    }
}

// out[g] = sigmoid(((sums[g]/max(cnt,1)) @ W2) @ W3)
__global__ void k_final(const float* __restrict__ sums, const int* __restrict__ bound,
                        const float* __restrict__ W2, const float* __restrict__ W3,
                        float* __restrict__ out) {
    int g = threadIdx.x;
    if (g >= NUM_GRAPHS) return;
    float c = fmaxf((float)(bound[g + 1] - bound[g]), 1.f);
    float p[DIM];
#pragma unroll
    for (int k = 0; k < DIM; ++k) p[k] = sums[g * DIM + k] / c;
    float z = 0.f;
#pragma unroll
    for (int j = 0; j < DIM; ++j) {
        float t = 0.f;
#pragma unroll
        for (int k = 0; k < DIM; ++k) t += p[k] * W2[k * DIM + j];
        z += t * W3[j];
    }
    out[g] = 1.f / (1.f + expf(-z));
}

// ---------------------------------------------------------------------------
// Workspace (bytes):
//   h1     [0,         2000000)    100k x 10 fp16 (L2-resident)
//   pk     [2000000,  27624576)    391 x 16384 x 4B  (dst-bucketed)
//   pk2    [27624576, 43638912)    391 x 10240 x 4B  (src-bucketed, g baked)
//   r      [43638912, 45638912)    100k x 10 fp16 (L2-resident)
//   part   [45638912, 53646592)    782 x 2560 f32
//   cnt    [53646592, 53648156)    391 int  \
//   cnt2   [53648160, 53649724)    391 int   | zeroed by one 5696B memset
//   sums   [53649728, 53652288)    640 f32  /
//   bound  [53652288, 53652548)    65 int
// ---------------------------------------------------------------------------
extern "C" void kernel_launch(void* const* d_in, const int* in_sizes, int n_in,
                              void* d_out, int out_size, void* d_ws, size_t ws_size,
                              hipStream_t stream) {
    const float* feat = (const float*)d_in[0];
    const float* W1   = (const float*)d_in[1];
    const float* W2   = (const float*)d_in[2];
    const float* W3   = (const float*)d_in[3];
    const int*   src  = (const int*)d_in[4];
    const int*   dst  = (const int*)d_in[5];
    const int*   gids = (const int*)d_in[6];
    float*       out  = (float*)d_out;

    char* ws = (char*)d_ws;
    __half* h1    = (__half*)(ws);
    int*    pk    = (int*)(ws + 2000000);
    int*    pk2   = (int*)(ws + 27624576);
    __half* r     = (__half*)(ws + 43638912);
    float*  part  = (float*)(ws + 45638912);
    int*    cnt   = (int*)(ws + 53646592);
    int*    cnt2  = (int*)(ws + 53648160);
    float*  sums  = (float*)(ws + 53649728);
    int*    bound = (int*)(ws + 53652288);

    // zero cnt + cnt2 + sums in one tiny DMA
    hipMemsetAsync(ws + 53646592, 0, 5696, stream);

    k_front<<<PLACE_BLOCKS + GEMM_BLOCKS, 512, 0, stream>>>(feat, W1, h1, gids, bound,
                                                            src, dst, cnt, cnt2, pk, pk2);
    k_spmm1     <<<NCHUNK, 512, 0, stream>>>(h1, cnt, pk, part);
    k_merge_relu<<<NB, 256, 0, stream>>>(part, r);
    k_pass2     <<<NB, 512, 0, stream>>>(r, cnt2, pk2, sums);

    k_final<<<1, 64, 0, stream>>>(sums, bound, W2, W3, out);
}

// Round 14
// 206.020 us; speedup vs baseline: 2.1000x; 2.1000x over previous
//
#include <hip/hip_runtime.h>
#include <hip/hip_fp16.h>

#define N_NODES 100000
#define N_EDGES 3200000
#define NUM_FEATURES 128
#define DIM 10
#define NUM_GRAPHS 64

#define BSHIFT 8                             // 256 nodes per bucket
#define BSIZE (1 << BSHIFT)
#define NB ((N_NODES + BSIZE - 1) / BSIZE)   // 391 buckets
#define CHUNKS 4                             // spmm1 chunks per bucket
#define PCHUNKS 4                            // pass2 chunks per bucket
#define EPB 6250                             // edges per placement block
#define PLACE_BLOCKS 512                     // 512 * 6250 = 3.2M exact
#define NQUAD 25000                          // 100k nodes / 4 per 32-lane group
#define GEMM_BLOCKS 1563                     // ceil(25000*32 / 512)
#define BOUND_BLOCKS 196                     // ceil(100000 / 512)
#define TILE (BSIZE * DIM)                   // 2560 floats per bucket part tile
#define CAP 2560                             // max edges per spmm1 chunk (mean 2046, +22 sigma)
#define CAPB 16384                           // per-bucket pk region capacity (+90 sigma)
#define NCHUNK (NB * CHUNKS)                 // 1564
#define NCHUNK2 (NB * PCHUNKS)               // 1564
#define ACC_STRIDE 11

// f32 add of DPP row-rotated value (VALU pipe)
#define DPP_ROR_ADD(v, n)                                                        \
    (v) += __int_as_float(__builtin_amdgcn_update_dpp(                           \
        0, __float_as_int(v), 0x120 | (n), 0xF, 0xF, false))

// ---------------------------------------------------------------------------
// FINAL KERNEL (session best: 205.2us, R12 config). Fused front-end.
// Lessons ledger (all measured on MI355X):
//  R3  no cross-block fences/fusion: device fence = per-XCD L2 wb+inv, 3x.
//  R5  4-node batching + dwordx4 W1 loads: the one real GEMM win (TA relief).
//  R6  no pk line-padding (institutionalizes partial-line write-amp).
//  R7  no k-indexed LDS W1 (8.6x bank conflicts).
//  R8/R9 W1 is loaded once/thread already; launch_bounds/asm-pin are no-ops.
//  R10 no 32B padded gather rows (2x bytes + 2x VALU).
//  R11 no f32 gather table (4MB breaks pass2's per-XCD L2 residency).
//  R12 place-block count 256 vs 512 is a wash; 512 measured best overall.
//  R13 no src-major pass2: dst-major's <=2-graph-span register accumulation
//      is the invariant that makes pass2 cheap; src-major = LDS atomic storm.
// ---------------------------------------------------------------------------
__global__ __launch_bounds__(512) void k_front(const float* __restrict__ feat,
                                               const float* __restrict__ W1,
                                               __half* __restrict__ h1,
                                               const int* __restrict__ gids,
                                               int* __restrict__ bound,
                                               const int* __restrict__ src,
                                               const int* __restrict__ dst,
                                               int* __restrict__ cnt,
                                               int* __restrict__ pk) {
    __shared__ int hd[NB];      // placement: per-block histogram
    __shared__ int cb[NB];      // placement: absolute write cursors

    if (blockIdx.x < PLACE_BLOCKS) {
        int base0 = blockIdx.x * EPB;
        for (int t = threadIdx.x; t < NB; t += 512) hd[t] = 0;
        __syncthreads();

        // phase 1: histogram (coalesced 4-batched dst loads)
        {
            int i = threadIdx.x;
            for (; i + 1536 < EPB; i += 2048) {
                int d0 = dst[base0 + i],        d1 = dst[base0 + i + 512];
                int d2 = dst[base0 + i + 1024], d3 = dst[base0 + i + 1536];
                atomicAdd(&hd[d0 >> BSHIFT], 1);
                atomicAdd(&hd[d1 >> BSHIFT], 1);
                atomicAdd(&hd[d2 >> BSHIFT], 1);
                atomicAdd(&hd[d3 >> BSHIFT], 1);
            }
            for (; i < EPB; i += 512)
                atomicAdd(&hd[dst[base0 + i] >> BSHIFT], 1);
        }
        __syncthreads();

        // phase 2: reserve contiguous range in bucket region via global atomic
        for (int t = threadIdx.x; t < NB; t += 512) {
            int c = hd[t];
            int o = c ? atomicAdd(&cnt[t], c) : 0;
            cb[t] = t * CAPB + o;
        }
        __syncthreads();

        // phase 3: place (dst re-read is L2-hot; 1 LDS atomic/edge; clamp=safety)
        {
            int i = threadIdx.x;
            for (; i + 1536 < EPB; i += 2048) {
                int d0 = dst[base0 + i],        d1 = dst[base0 + i + 512];
                int d2 = dst[base0 + i + 1024], d3 = dst[base0 + i + 1536];
                int s0 = src[base0 + i],        s1 = src[base0 + i + 512];
                int s2 = src[base0 + i + 1024], s3 = src[base0 + i + 1536];
                int q0 = atomicAdd(&cb[d0 >> BSHIFT], 1);
                int q1 = atomicAdd(&cb[d1 >> BSHIFT], 1);
                int q2 = atomicAdd(&cb[d2 >> BSHIFT], 1);
                int q3 = atomicAdd(&cb[d3 >> BSHIFT], 1);
                if (q0 < ((d0 >> BSHIFT) + 1) * CAPB) pk[q0] = ((d0 & (BSIZE - 1)) << 17) | s0;
                if (q1 < ((d1 >> BSHIFT) + 1) * CAPB) pk[q1] = ((d1 & (BSIZE - 1)) << 17) | s1;
                if (q2 < ((d2 >> BSHIFT) + 1) * CAPB) pk[q2] = ((d2 & (BSIZE - 1)) << 17) | s2;
                if (q3 < ((d3 >> BSHIFT) + 1) * CAPB) pk[q3] = ((d3 & (BSIZE - 1)) << 17) | s3;
            }
            for (; i < EPB; i += 512) {
                int d = dst[base0 + i];
                int s = src[base0 + i];
                int q = atomicAdd(&cb[d >> BSHIFT], 1);
                if (q < ((d >> BSHIFT) + 1) * CAPB) pk[q] = ((d & (BSIZE - 1)) << 17) | s;
            }
        }
        return;
    }

    // ---- GEMM half: 4 nodes per 32-lane group ----
    int bb = blockIdx.x - PLACE_BLOCKS;

    // fused graph-boundary computation (gids sorted)
    int nb2 = bb * 512 + threadIdx.x;
    if (bb < BOUND_BLOCKS && nb2 < N_NODES) {
        int g  = gids[nb2];
        int gp = nb2 ? gids[nb2 - 1] : -1;
        for (int v = gp + 1; v <= g; ++v) bound[v] = nb2;
        if (nb2 == N_NODES - 1)
            for (int v = g + 1; v <= NUM_GRAPHS; ++v) bound[v] = N_NODES;
    }

    int gid  = bb * 512 + threadIdx.x;
    int quad = gid >> 5;                 // node quad id
    int lane = gid & 31;
    if (quad >= NQUAD) return;

    // lane's W1 slice (rows lane*4..lane*4+3, 160B contiguous) as 10 dwordx4
    float wf[40];
    {
        const float4* W14 = reinterpret_cast<const float4*>(W1 + lane * 40);
#pragma unroll
        for (int m = 0; m < 10; ++m) {
            float4 q = W14[m];
            wf[4 * m]     = q.x;
            wf[4 * m + 1] = q.y;
            wf[4 * m + 2] = q.z;
            wf[4 * m + 3] = q.w;
        }
    }

    int nbase = quad * 4;
    float4 f[4];
#pragma unroll
    for (int n = 0; n < 4; ++n)
        f[n] = *reinterpret_cast<const float4*>(feat + (size_t)(nbase + n) * NUM_FEATURES + lane * 4);

    float acc[4][DIM];
#pragma unroll
    for (int n = 0; n < 4; ++n)
#pragma unroll
        for (int k = 0; k < DIM; ++k) acc[n][k] = 0.f;

#pragma unroll
    for (int n = 0; n < 4; ++n) {
        float fv[4] = {f[n].x, f[n].y, f[n].z, f[n].w};
#pragma unroll
        for (int j = 0; j < 4; ++j)
#pragma unroll
            for (int k = 0; k < DIM; ++k)
                acc[n][k] += fv[j] * wf[j * DIM + k];
    }

    // reduce over 32 lanes: 4 in-row DPP rotate-adds (VALU) + 1 shfl_xor(16)
#pragma unroll
    for (int n = 0; n < 4; ++n)
#pragma unroll
        for (int k = 0; k < DIM; ++k) {
            float v = acc[n][k];
            DPP_ROR_ADD(v, 1);
            DPP_ROR_ADD(v, 2);
            DPP_ROR_ADD(v, 4);
            DPP_ROR_ADD(v, 8);
            acc[n][k] = v + __shfl_xor(v, 16);
        }

    if (lane == 0) {
        __half2* o = (__half2*)h1;
#pragma unroll
        for (int n = 0; n < 4; ++n)
#pragma unroll
            for (int j = 0; j < 5; ++j)
                o[(size_t)(nbase + n) * 5 + j] = __floats2half2_rn(acc[n][2 * j], acc[n][2 * j + 1]);
    }
}

// ---------------------------------------------------------------------------
// Pass 1 SpMM (CHUNKS=4): in-block counting sort to exact dst-loc (eh stash,
// 2 LDS atomics/edge, 4-batched pk loads), exclusive-owner segmented gather
// (12 slots x 5 lanes, 8-deep), register acc, non-atomic writes.
// ---------------------------------------------------------------------------
__global__ __launch_bounds__(512) void k_spmm1(const __half* __restrict__ h,
                                               const int* __restrict__ cnt,
                                               const int* __restrict__ pk,
                                               float* __restrict__ part) {
    __shared__ int eh[CAP];
    __shared__ int srt[CAP];
    __shared__ int hist[BSIZE];
    __shared__ int cur[BSIZE];

    int b     = blockIdx.x / CHUNKS;
    int chunk = blockIdx.x % CHUNKS;
    int s0  = b * CAPB;
    int len = cnt[b];
    int c0  = s0 + (len * chunk) / CHUNKS;
    int c1  = s0 + (len * (chunk + 1)) / CHUNKS;
    int n   = c1 - c0;
    int nc  = min(n, CAP);

    for (int t = threadIdx.x; t < BSIZE; t += 512) hist[t] = 0;
    __syncthreads();

    {
        int i = threadIdx.x;
        for (; i + 1536 < nc; i += 2048) {
            int p0 = pk[c0 + i],        p1 = pk[c0 + i + 512];
            int p2 = pk[c0 + i + 1024], p3 = pk[c0 + i + 1536];
            eh[i] = p0; eh[i + 512] = p1; eh[i + 1024] = p2; eh[i + 1536] = p3;
            atomicAdd(&hist[p0 >> 17], 1);
            atomicAdd(&hist[p1 >> 17], 1);
            atomicAdd(&hist[p2 >> 17], 1);
            atomicAdd(&hist[p3 >> 17], 1);
        }
        for (; i < nc; i += 512) {
            int p = pk[c0 + i];
            eh[i] = p;
            atomicAdd(&hist[p >> 17], 1);
        }
    }
    __syncthreads();

    if (threadIdx.x < 64) {
        int l = threadIdx.x;
        int carry = 0;
#pragma unroll
        for (int j = 0; j < 4; ++j) {
            int x = hist[j * 64 + l];
            int v = x;
#pragma unroll
            for (int off = 1; off < 64; off <<= 1) {
                int t2 = __shfl_up(v, off);
                if (l >= off) v += t2;
            }
            cur[j * 64 + l] = carry + v - x;
            carry += __shfl(v, 63);
        }
    }
    __syncthreads();

    for (int i = threadIdx.x; i < nc; i += 512) {
        int p = eh[i];
        int pos = atomicAdd(&cur[p >> 17], 1);
        srt[pos] = p;
    }
    __syncthreads();

    int wave = threadIdx.x >> 6;
    int lane = threadIdx.x & 63;
    int slot = lane / 5;            // 0..12 (12 = idle lanes 60..63)
    int l    = lane - slot * 5;     // half2 index within the row
    float* pb = part + (size_t)blockIdx.x * TILE;
    const __half2* h2 = (const __half2*)h;

    if (slot < 12) {
        int g = wave * 12 + slot;   // 0..95
        for (int loc = g; loc < BSIZE; loc += 96) {
            int e0 = loc ? cur[loc - 1] : 0;
            int e1 = cur[loc];
            float ax0 = 0.f, ay0 = 0.f, ax1 = 0.f, ay1 = 0.f;
            float ax2 = 0.f, ay2 = 0.f, ax3 = 0.f, ay3 = 0.f;
            int e = e0;
            for (; e + 7 < e1; e += 8) {
                float2 v0 = __half22float2(h2[(size_t)(srt[e]     & 0x1FFFF) * 5 + l]);
                float2 v1 = __half22float2(h2[(size_t)(srt[e + 1] & 0x1FFFF) * 5 + l]);
                float2 v2 = __half22float2(h2[(size_t)(srt[e + 2] & 0x1FFFF) * 5 + l]);
                float2 v3 = __half22float2(h2[(size_t)(srt[e + 3] & 0x1FFFF) * 5 + l]);
                float2 v4 = __half22float2(h2[(size_t)(srt[e + 4] & 0x1FFFF) * 5 + l]);
                float2 v5 = __half22float2(h2[(size_t)(srt[e + 5] & 0x1FFFF) * 5 + l]);
                float2 v6 = __half22float2(h2[(size_t)(srt[e + 6] & 0x1FFFF) * 5 + l]);
                float2 v7 = __half22float2(h2[(size_t)(srt[e + 7] & 0x1FFFF) * 5 + l]);
                ax0 += v0.x + v4.x; ay0 += v0.y + v4.y;
                ax1 += v1.x + v5.x; ay1 += v1.y + v5.y;
                ax2 += v2.x + v6.x; ay2 += v2.y + v6.y;
                ax3 += v3.x + v7.x; ay3 += v3.y + v7.y;
            }
            for (; e < e1; ++e) {
                float2 v = __half22float2(h2[(size_t)(srt[e] & 0x1FFFF) * 5 + l]);
                ax0 += v.x; ay0 += v.y;
            }
            pb[loc * DIM + 2 * l]     = (ax0 + ax1) + (ax2 + ax3);
            pb[loc * DIM + 2 * l + 1] = (ay0 + ay1) + (ay2 + ay3);
        }
    }
    __syncthreads();

    // overflow fallback (statistically never; correctness guard)
    for (int i = CAP + threadIdx.x; i < n; i += 512) {
        int p = pk[c0 + i];
        int loc = p >> 17, s = p & 0x1FFFF;
#pragma unroll
        for (int j = 0; j < 5; ++j) {
            float2 v = __half22float2(h2[(size_t)s * 5 + j]);
            atomicAdd(&pb[loc * DIM + 2 * j], v.x);
            atomicAdd(&pb[loc * DIM + 2 * j + 1], v.y);
        }
    }
}

// merge CHUNKS partials + fused relu -> r (fp16, compact stride 10)
__global__ __launch_bounds__(256) void k_merge_relu(const float* __restrict__ part,
                                                    __half* __restrict__ r) {
    int b     = blockIdx.x;
    int nbase = b << BSHIFT;
    const float* p0 = part + (size_t)(b * CHUNKS) * TILE;
    __half2* r2 = (__half2*)r;
    for (int t = threadIdx.x; t < TILE / 2; t += 256) {
        float sx = 0.f, sy = 0.f;
#pragma unroll
        for (int c = 0; c < CHUNKS; ++c) {
            float2 v = ((const float2*)(p0 + (size_t)c * TILE))[t];
            sx += v.x; sy += v.y;
        }
        int ebase = nbase * DIM + 2 * t;
        if (ebase < N_NODES * DIM)
            r2[(size_t)nbase * 5 + t] = __floats2half2_rn(fmaxf(sx, 0.f), fmaxf(sy, 0.f));
    }
}

// ---------------------------------------------------------------------------
// Pass 2 (dst-major, proven): bucket spans <=1 graph boundary in ~all cases.
// Branchless dual REGISTER accumulator (the invariant that makes this cheap),
// 8-deep batched pk->r loads, global-atomic flush of <=2 graph rows.
// ---------------------------------------------------------------------------
__global__ __launch_bounds__(512) void k_pass2(const __half* __restrict__ r,
                                               const int* __restrict__ cnt,
                                               const int* __restrict__ pk,
                                               const int* __restrict__ bound,
                                               float* __restrict__ sums) {
    __shared__ float acc[NUM_GRAPHS * ACC_STRIDE];

    int b     = blockIdx.x / PCHUNKS;
    int chunk = blockIdx.x % PCHUNKS;
    int nbase = b << BSHIFT;
    int nlast = min(nbase + BSIZE - 1, N_NODES - 1);

    int glo = 0, ghx = NUM_GRAPHS - 1;
#pragma unroll
    for (int it = 0; it < 6; ++it) {
        int mid = (glo + ghx + 1) >> 1;
        if (bound[mid] <= nbase) glo = mid; else ghx = mid - 1;
    }
    int lo2 = 0, hi2 = NUM_GRAPHS - 1;
#pragma unroll
    for (int it = 0; it < 6; ++it) {
        int mid = (lo2 + hi2 + 1) >> 1;
        if (bound[mid] <= nlast) lo2 = mid; else hi2 = mid - 1;
    }
    int ghi  = lo2;
    int span = ghi - glo;

    for (int t = threadIdx.x; t < (span + 1) * DIM; t += 512)
        acc[(glo + t / DIM) * ACC_STRIDE + t % DIM] = 0.f;
    __syncthreads();

    int s0  = b * CAPB;
    int len = cnt[b];
    int c0  = s0 + (len * chunk) / PCHUNKS;
    int c1  = s0 + (len * (chunk + 1)) / PCHUNKS;

    int wave = threadIdx.x >> 6;
    int lane = threadIdx.x & 63;
    int slot = lane / 5;
    int l    = lane - slot * 5;
    const __half2* r2 = (const __half2*)r;

    if (slot < 12) {
        const int STR = 96;
        int q = wave * 12 + slot;
        int e = c0 + q;
        if (span <= 1) {
            int gA  = glo;
            int gB  = (span == 1) ? glo + 1 : glo;
            int cut = (span == 1) ? (bound[glo + 1] - nbase) : BSIZE;
            float axA = 0.f, ayA = 0.f, axB = 0.f, ayB = 0.f;
            for (; e + 7 * STR < c1; e += 8 * STR) {
                int p[8];
#pragma unroll
                for (int u = 0; u < 8; ++u) p[u] = pk[e + u * STR];
                float2 v[8];
#pragma unroll
                for (int u = 0; u < 8; ++u)
                    v[u] = __half22float2(r2[(size_t)(p[u] & 0x1FFFF) * 5 + l]);
#pragma unroll
                for (int u = 0; u < 8; ++u) {
                    bool a = (p[u] >> 17) < cut;
                    axA += a ? v[u].x : 0.f;  ayA += a ? v[u].y : 0.f;
                    axB += a ? 0.f : v[u].x;  ayB += a ? 0.f : v[u].y;
                }
            }
            for (; e < c1; e += STR) {
                int p = pk[e];
                float2 v = __half22float2(r2[(size_t)(p & 0x1FFFF) * 5 + l]);
                bool a = (p >> 17) < cut;
                axA += a ? v.x : 0.f;  ayA += a ? v.y : 0.f;
                axB += a ? 0.f : v.x;  ayB += a ? 0.f : v.y;
            }
            atomicAdd(&acc[gA * ACC_STRIDE + 2 * l], axA);
            atomicAdd(&acc[gA * ACC_STRIDE + 2 * l + 1], ayA);
            if (span == 1) {
                atomicAdd(&acc[gB * ACC_STRIDE + 2 * l], axB);
                atomicAdd(&acc[gB * ACC_STRIDE + 2 * l + 1], ayB);
            }
        } else {
            for (; e < c1; e += STR) {
                int p   = pk[e];
                int loc = p >> 17;
                float2 v = __half22float2(r2[(size_t)(p & 0x1FFFF) * 5 + l]);
                int g = glo;
                for (int gg = glo + 1; gg <= ghi; ++gg)
                    g += (loc >= bound[gg] - nbase) ? 1 : 0;
                atomicAdd(&acc[g * ACC_STRIDE + 2 * l], v.x);
                atomicAdd(&acc[g * ACC_STRIDE + 2 * l + 1], v.y);
            }
        }
    }
    __syncthreads();

    for (int t = threadIdx.x; t < (span + 1) * DIM; t += 512) {
        int g = glo + t / DIM;
        float v = acc[g * ACC_STRIDE + t % DIM];
        if (v != 0.f) atomicAdd(&sums[g * DIM + t % DIM], v);
    }
}

// out[g] = sigmoid(((sums[g]/max(cnt,1)) @ W2) @ W3)
__global__ void k_final(const float* __restrict__ sums, const int* __restrict__ bound,
                        const float* __restrict__ W2, const float* __restrict__ W3,
                        float* __restrict__ out) {
    int g = threadIdx.x;
    if (g >= NUM_GRAPHS) return;
    float c = fmaxf((float)(bound[g + 1] - bound[g]), 1.f);
    float p[DIM];
#pragma unroll
    for (int k = 0; k < DIM; ++k) p[k] = sums[g * DIM + k] / c;
    float z = 0.f;
#pragma unroll
    for (int j = 0; j < DIM; ++j) {
        float t = 0.f;
#pragma unroll
        for (int k = 0; k < DIM; ++k) t += p[k] * W2[k * DIM + j];
        z += t * W3[j];
    }
    out[g] = 1.f / (1.f + expf(-z));
}

// ---------------------------------------------------------------------------
// Workspace (bytes):
//   h1     [0,         2000000)    100k x 10 fp16 (L2-resident)
//   pk     [2000000,  27624576)    391 buckets x 16384 slots x 4B
//   r      [27624576, 29624576)    100k x 10 fp16 (L2-resident)
//   part   [29624576, 45639936)    1564 x 2560 f32
//   cnt    [45639936, 45641500)    391 int   \  zeroed by one 4128B memset
//   sums   [45641504, 45644064)    640 f32   /
//   bound  [45644064, 45644324)    65 int
// ---------------------------------------------------------------------------
extern "C" void kernel_launch(void* const* d_in, const int* in_sizes, int n_in,
                              void* d_out, int out_size, void* d_ws, size_t ws_size,
                              hipStream_t stream) {
    const float* feat = (const float*)d_in[0];
    const float* W1   = (const float*)d_in[1];
    const float* W2   = (const float*)d_in[2];
    const float* W3   = (const float*)d_in[3];
    const int*   src  = (const int*)d_in[4];
    const int*   dst  = (const int*)d_in[5];
    const int*   gids = (const int*)d_in[6];
    float*       out  = (float*)d_out;

    char* ws = (char*)d_ws;
    __half* h1    = (__half*)(ws);
    int*    pk    = (int*)(ws + 2000000);
    __half* r     = (__half*)(ws + 27624576);
    float*  part  = (float*)(ws + 29624576);
    int*    cnt   = (int*)(ws + 45639936);
    float*  sums  = (float*)(ws + 45641504);
    int*    bound = (int*)(ws + 45644064);

    // zero cnt (391 int) + pad + sums (640 f32) in one tiny DMA
    hipMemsetAsync(ws + 45639936, 0, 4128, stream);

    k_front<<<PLACE_BLOCKS + GEMM_BLOCKS, 512, 0, stream>>>(feat, W1, h1, gids, bound,
                                                            src, dst, cnt, pk);
    k_spmm1     <<<NCHUNK, 512, 0, stream>>>(h1, cnt, pk, part);
    k_merge_relu<<<NB, 256, 0, stream>>>(part, r);
    k_pass2     <<<NCHUNK2, 512, 0, stream>>>(r, cnt, pk, bound, sums);

    k_final<<<1, 64, 0, stream>>>(sums, bound, W2, W3, out);
}